// Round 15
// baseline (123.773 us; speedup 1.0000x reference)
//
#include <hip/hip_runtime.h>
#include <cmath>

// GRU-D cell: B=16384, F=U=512.
//   prep_pack: xd,hd -> A1=[xd|hd] bf16 (B x 1024); weights -> bf16 B^T
//   gemm6<0>: A1 @ Wzr -> sigmoid -> Zb (bf16), RH = r*hd (bf16)  [256x256]
//   gemm6<1>: [xd|RH] @ Wht -> tanh, blend with Zb, hd from A1 -> out [256x128]
// R15: prep gets the GEMM's pipelined staging: 1024 blocks x 16 rows,
// 4 LDS buffers (16KB: 2 rows inp + h), depth-3 prefetch, counted VMC(8)
// per chunk -- loads continuously in flight (R12's issue->vmcnt(0)->exit
// pattern left loads idle ~40% of block lifetime; fill kernel proves 6.8TB/s
// is reachable). pack + gemm6 byte-identical to R14 (passed).

typedef __bf16 bf16x8 __attribute__((ext_vector_type(8)));
typedef __bf16 bf16x4 __attribute__((ext_vector_type(4)));
typedef float f32x4 __attribute__((ext_vector_type(4)));

typedef __attribute__((address_space(3))) void lds_vp;
typedef const __attribute__((address_space(1))) void g_vp;

#define VMC(N) asm volatile("s_waitcnt vmcnt(" N ")" ::: "memory")

__device__ __forceinline__ void barrier_() {
  asm volatile("" ::: "memory");
  __builtin_amdgcn_s_barrier();
  asm volatile("" ::: "memory");
}

__device__ __forceinline__ float sigmoidf_(float x) { return 1.f / (1.f + expf(-x)); }

// ---------------- prep (pipelined gload_lds) + pack (LDS transpose) ----------------
__global__ __launch_bounds__(256, 2) void prep_pack_k(
    const float* __restrict__ inp, const float* __restrict__ h_prev,
    const float* __restrict__ gxd, const float* __restrict__ ghd,
    const float* __restrict__ mimp, __bf16* __restrict__ A1,
    const float* __restrict__ Wz, const float* __restrict__ Uz,
    const float* __restrict__ Wr, const float* __restrict__ Ur,
    const float* __restrict__ Wh, const float* __restrict__ Uh,
    __bf16* __restrict__ Wzr, __bf16* __restrict__ Wht) {
  __shared__ __align__(16) float SHF[16384];  // 64KB: 4 bufs x 16KB (2 rows)
  int tid = threadIdx.x, lane = tid & 63, wid = tid >> 6;
  if (blockIdx.x < 1024) {
    int r0 = blockIdx.x * 16;                 // 16 rows per block, 8 chunks x 2
    int c8 = (tid & 63) << 3;
    int half = (tid >> 6) & 1;                // 0: xd, 1: hd (wave-uniform)
    int row1 = tid >> 7;                      // row within chunk (0/1)
    // loop-invariant per-column params
    float gc[8], mi[8];
    if (half == 0) {
      float4 a = *(const float4*)(gxd + c8), b = *(const float4*)(gxd + c8 + 4);
      float4 p = *(const float4*)(mimp + c8), q = *(const float4*)(mimp + c8 + 4);
#pragma unroll
      for (int j = 0; j < 4; ++j) {
        gc[j] = -fmaxf(0.f, ((const float*)&a)[j]);
        gc[j + 4] = -fmaxf(0.f, ((const float*)&b)[j]);
        mi[j] = ((const float*)&p)[j];
        mi[j + 4] = ((const float*)&q)[j];
      }
    } else {
      float4 a = *(const float4*)(ghd + c8), b = *(const float4*)(ghd + c8 + 4);
#pragma unroll
      for (int j = 0; j < 4; ++j) {
        gc[j] = -fmaxf(0.f, ((const float*)&a)[j]);
        gc[j + 4] = -fmaxf(0.f, ((const float*)&b)[j]);
      }
    }
    // stage one 2-row chunk (12KB inp + 4KB h) into buffer b; 4 loads/wave
    auto stage = [&](int c, int b) {
      const char* gi = (const char*)(inp + (size_t)(r0 + c * 2) * 1536);
      const char* gh = (const char*)(h_prev + (size_t)(r0 + c * 2) * 512);
      char* dst = (char*)SHF + b * 16384;
#pragma unroll
      for (int i = 0; i < 3; ++i) {
        int seg = i * 4 + wid;                // 1KB segments of inp (12)
        __builtin_amdgcn_global_load_lds((g_vp*)(gi + seg * 1024 + lane * 16),
                                         (lds_vp*)(dst + seg * 1024), 16, 0, 0);
      }
      __builtin_amdgcn_global_load_lds((g_vp*)(gh + wid * 1024 + lane * 16),
                                       (lds_vp*)(dst + 12288 + wid * 1024), 16, 0, 0);
    };
    stage(0, 0); stage(1, 1); stage(2, 2);    // 12 loads/wave in flight
    for (int c = 0; c < 8; ++c) {
      if (c < 6) { VMC("8"); } else if (c == 6) { VMC("4"); } else { VMC("0"); }
      barrier_();                             // chunk c visible to all waves
      if (c + 3 < 8) stage(c + 3, (c + 3) & 3);  // overwrites buf freed at c-1
      const float* buf = SHF + (c & 3) * 4096;
      int grow = r0 + c * 2 + row1;
      bf16x8 o;
      if (half == 0) {
        const float* xr = buf + row1 * 1536 + c8;
        float xv[8], mv[8], dv[8];
        *(float4*)&xv[0] = *(const float4*)(xr);
        *(float4*)&xv[4] = *(const float4*)(xr + 4);
        *(float4*)&mv[0] = *(const float4*)(xr + 512);
        *(float4*)&mv[4] = *(const float4*)(xr + 516);
        *(float4*)&dv[0] = *(const float4*)(xr + 1024);
        *(float4*)&dv[4] = *(const float4*)(xr + 1028);
#pragma unroll
        for (int j = 0; j < 8; ++j) {
          float g = __expf(gc[j] * dv[j]);
          float xd = mv[j] * xv[j] + (1.f - mv[j]) * (g * xv[j] + (1.f - g) * mi[j]);
          o[j] = (__bf16)xd;
        }
        *(bf16x8*)(A1 + (size_t)grow * 1024 + c8) = o;
      } else {
        const float* dr = buf + row1 * 1536 + 1024 + c8;
        const float* hr = buf + 3072 + row1 * 512 + c8;
        float dv[8], hv[8];
        *(float4*)&dv[0] = *(const float4*)(dr);
        *(float4*)&dv[4] = *(const float4*)(dr + 4);
        *(float4*)&hv[0] = *(const float4*)(hr);
        *(float4*)&hv[4] = *(const float4*)(hr + 4);
#pragma unroll
        for (int j = 0; j < 8; ++j) {
          float hd = __expf(gc[j] * dv[j]) * hv[j];
          o[j] = (__bf16)hd;
        }
        *(bf16x8*)(A1 + (size_t)grow * 1024 + 512 + c8) = o;
      }
    }
  } else {
    // pack one 64x64 (k,n) tile, transposed, into dst[n][k] (ldk=1024)
    __bf16* Tb = (__bf16*)SHF;                // [64][65] bf16
    int bid = blockIdx.x - 1024;
    const float* S;
    __bf16* dst;
    int tk, tn, nadj;
    if (bid < 256) {           // Wzr: 16 k-tiles x 16 n-tiles
      tk = (bid >> 4) * 64; tn = (bid & 15) * 64;
      bool khi = tk >= 512, nhi = tn >= 512;
      S = nhi ? (khi ? Ur : Wr) : (khi ? Uz : Wz);
      nadj = nhi ? 512 : 0;
      dst = Wzr;
    } else {                   // Wht: 16 k-tiles x 8 n-tiles
      int b2 = bid - 256;
      tk = (b2 >> 3) * 64; tn = (b2 & 7) * 64;
      S = (tk >= 512) ? Uh : Wh;
      nadj = 0;
      dst = Wht;
    }
    int kadj = (tk >= 512) ? 512 : 0;
    int kl = tid >> 4, n4 = (tid & 15) << 2;
#pragma unroll
    for (int rr = 0; rr < 4; ++rr) {
      int k = rr * 16 + kl;
      float4 v = *(const float4*)(S + (size_t)(tk - kadj + k) * 512 + (tn - nadj) + n4);
      Tb[k * 65 + n4 + 0] = (__bf16)v.x;
      Tb[k * 65 + n4 + 1] = (__bf16)v.y;
      Tb[k * 65 + n4 + 2] = (__bf16)v.z;
      Tb[k * 65 + n4 + 3] = (__bf16)v.w;
    }
    __syncthreads();
    int k0 = (tid & 7) * 8;
#pragma unroll
    for (int h = 0; h < 2; ++h) {
      int nl = (tid >> 3) + h * 32;
      bf16x8 v;
#pragma unroll
      for (int i = 0; i < 8; ++i) v[i] = Tb[(k0 + i) * 65 + nl];
      *(bf16x8*)(dst + (size_t)(tn + nl) * 1024 + tk + k0) = v;
    }
  }
}

// ---------------- 4-buffer depth-3 GEMM (BM=256, BK=32) ----------------
// LDS packed layout (16B units): logical element (row m, 16B k-chunk ku in 0..3)
// stored at unit (m>>1)*8 + (((m&1)*4 + ku) ^ ((m>>1)&7)).
// Staging writes linear units; per-lane global source applies the inverse map.

template <int MODE>
__global__ __launch_bounds__(512, 1) void gemm6_k(
    const __bf16* __restrict__ A1, const __bf16* __restrict__ RH,
    const __bf16* __restrict__ Bt,
    __bf16* __restrict__ Zb, __bf16* __restrict__ RHout,
    const float* __restrict__ bza, const float* __restrict__ bzb,
    float* __restrict__ out) {
  constexpr int NI = (MODE == 0) ? 8 : 4;     // n-frags per wave
  constexpr int BN = NI * 32;                 // 256 / 128
  constexpr int BUNITS = BN * 4;              // B 16B-units per tile
  constexpr int SBUF = 1024 + BUNITS;         // A 1024 | B
  __shared__ bf16x8 ldsv[4 * SBUF];           // 128KB / 96KB
  constexpr int NT = 32;                      // K=1024, BK=32
// steady: 3 tiles in flight, drain oldest -> wait 2*NLD; tail: NLD; last: 0
#define VMC_D3() do { if constexpr (MODE == 0) { VMC("8"); } else { VMC("6"); } } while (0)
#define VMC_D2() do { if constexpr (MODE == 0) { VMC("4"); } else { VMC("3"); } } while (0)

  int bid = blockIdx.x;
  int swz = (bid & 7) * 32 + (bid >> 3);      // bijective XCD swizzle (256=8x32)
  int bm = swz >> 2, bn = swz & 3;            // 64 x 4
  int tid = threadIdx.x, lane = tid & 63, wid = tid >> 6;
  int wm = wid >> 1, wn = wid & 1;            // 4M x 2N waves: 64 x (NI*16)

  // per-lane staging source offsets (inverse of packed-swizzle map)
  auto inv = [&](int U, int ldb) {
    int r = U >> 3, s = (U & 7) ^ (r & 7);
    return (2 * r + (s >> 2)) * ldb + (s & 3) * 16;  // bytes
  };
  int UA0 = wid * 128 + lane, UA1 = UA0 + 64;
  int offA0 = inv(UA0, 2048), offA1 = inv(UA1, 2048);
  int offA0r = inv(UA0, 1024), offA1r = inv(UA1, 1024);  // MODE1 RH half
  int UB0 = (MODE == 0) ? (wid * 128 + lane) : (wid * 64 + lane);
  int offB0 = inv(UB0, 2048);
  int offB1 = (MODE == 0) ? inv(UB0 + 64, 2048) : 0;
  int ldsB = (MODE == 0) ? (wid * 128) : (wid * 64);   // wave-uniform

  auto stage = [&](int t, int buf) {
    const char* gA;
    int oA0, oA1;
    if (MODE == 0 || t < 16) {
      gA = (const char*)A1 + (size_t)bm * 256 * 2048 + t * 64;
      oA0 = offA0; oA1 = offA1;
    } else {
      gA = (const char*)RH + (size_t)bm * 256 * 1024 + (t - 16) * 64;
      oA0 = offA0r; oA1 = offA1r;
    }
    __builtin_amdgcn_global_load_lds((g_vp*)(gA + oA0),
        (lds_vp*)(ldsv + buf * SBUF + wid * 128), 16, 0, 0);
    __builtin_amdgcn_global_load_lds((g_vp*)(gA + oA1),
        (lds_vp*)(ldsv + buf * SBUF + wid * 128 + 64), 16, 0, 0);
    const char* gB = (const char*)Bt + (size_t)bn * BN * 2048 + t * 64;
    __builtin_amdgcn_global_load_lds((g_vp*)(gB + offB0),
        (lds_vp*)(ldsv + buf * SBUF + 1024 + ldsB), 16, 0, 0);
    if constexpr (MODE == 0) {
      __builtin_amdgcn_global_load_lds((g_vp*)(gB + offB1),
          (lds_vp*)(ldsv + buf * SBUF + 1024 + ldsB + 64), 16, 0, 0);
    }
  };

  // fragment read bases (16B units), loop-invariant
  int lr = (lane & 15) >> 1;
  int lo = ((lane & 1) << 2) | (lane >> 4);
  int aoff = lr * 8 + (lo ^ lr);
  int aB = wm * 256 + aoff;                   // + mf*64
  int bB = 1024 + wn * (NI * 64) + aoff;      // + nf*64

  f32x4 acc[4][NI] = {};

  stage(0, 0);
  stage(1, 1);
  stage(2, 2);
  VMC_D3();        // outstanding 3N -> <=2N: tile0 complete
  barrier_();

  for (int t = 0; t < NT; ++t) {
    int base = (t & 3) * SBUF;
    if (t + 3 < NT) stage(t + 3, (t + 3) & 3);

    bf16x8 bf[NI];
#pragma unroll
    for (int nf = 0; nf < NI; ++nf) bf[nf] = ldsv[base + bB + nf * 64];
    __builtin_amdgcn_s_setprio(1);
#pragma unroll
    for (int mf = 0; mf < 4; ++mf) {
      bf16x8 a = ldsv[base + aB + mf * 64];
#pragma unroll
      for (int nf = 0; nf < NI; ++nf)
        acc[mf][nf] = __builtin_amdgcn_mfma_f32_16x16x32_bf16(a, bf[nf],
                                                              acc[mf][nf], 0, 0, 0);
    }
    __builtin_amdgcn_s_setprio(0);

    // drain tile t+1's loads; keep t+2 (and t+3 if staged) in flight
    if (t + 3 < NT) { VMC_D3(); }
    else if (t + 2 < NT) { VMC_D2(); }
    else if (t + 1 < NT) { VMC("0"); }
    if (t + 1 < NT) barrier_();
  }

  // ---------------- epilogue ----------------
  int col16 = lane & 15, rgrp = lane >> 4;
#pragma unroll
  for (int mf = 0; mf < 4; ++mf) {
    int grow0 = bm * 256 + wm * 64 + mf * 16 + rgrp * 4;
#pragma unroll
    for (int nf = 0; nf < NI; ++nf) {
      int gc = bn * BN + wn * (NI * 16) + nf * 16 + col16;
      if constexpr (MODE == 0) {
        if (gc < 512) {  // z columns (nf-uniform: tile never straddles 512)
          float b = bza[gc];
#pragma unroll
          for (int j = 0; j < 4; ++j) {
            float z = sigmoidf_(acc[mf][nf][j] + b);
            Zb[(size_t)(grow0 + j) * 512 + gc] = (__bf16)z;
          }
        } else {       // r columns
          int c = gc - 512;
          float b = bzb[c];
#pragma unroll
          for (int j = 0; j < 4; ++j) {
            int grow = grow0 + j;
            float r = sigmoidf_(acc[mf][nf][j] + b);
            float hd = (float)A1[(size_t)grow * 1024 + 512 + c];
            RHout[(size_t)grow * 512 + c] = (__bf16)(r * hd);
          }
        }
      } else {
        float b = bza[gc];
#pragma unroll
        for (int j = 0; j < 4; ++j) {
          int grow = grow0 + j;
          float hh = tanhf(acc[mf][nf][j] + b);
          float hd = (float)A1[(size_t)grow * 1024 + 512 + gc];
          float z = (float)Zb[(size_t)grow * 512 + gc];
          out[(size_t)grow * 512 + gc] = (1.f - z) * hd + z * hh;
        }
      }
    }
  }
}

// ---------------- launch ----------------
extern "C" void kernel_launch(void* const* d_in, const int* in_sizes, int n_in,
                              void* d_out, int out_size, void* d_ws, size_t ws_size,
                              hipStream_t stream) {
  const float* inputs = (const float*)d_in[0];
  const float* h_prev = (const float*)d_in[1];
  const float* W_z = (const float*)d_in[2];
  const float* U_z = (const float*)d_in[3];
  const float* b_z = (const float*)d_in[4];
  const float* W_r = (const float*)d_in[5];
  const float* U_r = (const float*)d_in[6];
  const float* b_r = (const float*)d_in[7];
  const float* W_h = (const float*)d_in[8];
  const float* U_h = (const float*)d_in[9];
  const float* b_h = (const float*)d_in[10];
  const float* gxd = (const float*)d_in[11];
  const float* ghd = (const float*)d_in[12];
  const float* mimp = (const float*)d_in[13];
  float* out = (float*)d_out;

  char* ws = (char*)d_ws;
  __bf16* A1  = (__bf16*)(ws);                  // 16384x1024 bf16 = 32MB
  __bf16* RH  = (__bf16*)(ws + 33554432);       // 16384x512 bf16 = 16MB
  __bf16* Zb  = (__bf16*)(ws + 50331648);       // 16384x512 bf16 = 16MB
  __bf16* Wzr = (__bf16*)(ws + 67108864);       // 1024x1024 bf16 = 2MB
  __bf16* Wht = (__bf16*)(ws + 69206016);       // 512x1024 bf16  = 1MB

  prep_pack_k<<<1408, 256, 0, stream>>>(inputs, h_prev, gxd, ghd, mimp, A1,
                                        W_z, U_z, W_r, U_r, W_h, U_h, Wzr, Wht);
  gemm6_k<0><<<256, 512, 0, stream>>>(A1, RH, Wzr, Zb, RH, b_z, b_r, nullptr);
  gemm6_k<1><<<256, 512, 0, stream>>>(A1, RH, Wht, Zb, nullptr, b_h, nullptr, out);
}

// Round 16
// 116.789 us; speedup vs baseline: 1.0598x; 1.0598x over previous
//
#include <hip/hip_runtime.h>
#include <cmath>

// GRU-D cell: B=16384, F=U=512.
//   prep_pack: xd,hd -> A1=[xd|hd] bf16 (B x 1024); weights -> bf16 B^T
//   gemm7<0>: A1 @ Wzr -> sigmoid -> Zb (bf16), RH = r*hd (bf16)  [128x256]
//   gemm7<1>: [xd|RH] @ Wht -> tanh, blend with Zb, hd from A1 -> out [128x128]
// R16: TRUE 2 blocks/CU. R6/R7's "2 blocks/CU" experiment was void:
// __launch_bounds__ 2nd arg is waves/SIMD, so (512,2) pinned 1 block/CU
// (matches the 19% occupancy measured). Now: BM=128 -> grid 512 = 2 blocks/CU
// chip-wide, LDS 48/32KB (2 bufs), launch_bounds(512,4). R4-proven
// 2-buffer VMC(0)+barrier loop; one block's drain hides under the co-resident
// block's MFMA. prep/pack = R12 (best total 119.6).

typedef __bf16 bf16x8 __attribute__((ext_vector_type(8)));
typedef __bf16 bf16x4 __attribute__((ext_vector_type(4)));
typedef float f32x4 __attribute__((ext_vector_type(4)));

typedef __attribute__((address_space(3))) void lds_vp;
typedef const __attribute__((address_space(1))) void g_vp;

#define VMC(N) asm volatile("s_waitcnt vmcnt(" N ")" ::: "memory")

__device__ __forceinline__ void barrier_() {
  asm volatile("" ::: "memory");
  __builtin_amdgcn_s_barrier();
  asm volatile("" ::: "memory");
}

__device__ __forceinline__ float sigmoidf_(float x) { return 1.f / (1.f + expf(-x)); }

// ---------------- prep (global_load_lds staged) + pack (LDS transpose) ----------------
__global__ __launch_bounds__(256) void prep_pack_k(
    const float* __restrict__ inp, const float* __restrict__ h_prev,
    const float* __restrict__ gxd, const float* __restrict__ ghd,
    const float* __restrict__ mimp, __bf16* __restrict__ A1,
    const float* __restrict__ Wz, const float* __restrict__ Uz,
    const float* __restrict__ Wr, const float* __restrict__ Ur,
    const float* __restrict__ Wh, const float* __restrict__ Uh,
    __bf16* __restrict__ Wzr, __bf16* __restrict__ Wht) {
  __shared__ __align__(16) float SHF[8192];   // 32KB, aliased by pack branch
  int tid = threadIdx.x;
  int lane = tid & 63, wid = tid >> 6;
  if (blockIdx.x < 4096) {
    int r0 = blockIdx.x * 4;                  // 4 rows per block
    const char* gi = (const char*)(inp + (size_t)r0 * 1536);
    const char* gh = (const char*)(h_prev + (size_t)r0 * 512);
#pragma unroll
    for (int i = 0; i < 6; ++i) {
      int seg = i * 4 + wid;                  // 1KB segment
      __builtin_amdgcn_global_load_lds((g_vp*)(gi + seg * 1024 + lane * 16),
                                       (lds_vp*)((char*)SHF + seg * 1024), 16, 0, 0);
    }
#pragma unroll
    for (int i = 0; i < 2; ++i) {
      int seg = i * 4 + wid;
      __builtin_amdgcn_global_load_lds((g_vp*)(gh + seg * 1024 + lane * 16),
                                       (lds_vp*)((char*)SHF + 24576 + seg * 1024), 16, 0, 0);
    }
    int c8 = (tid & 63) << 3;
    int row2 = tid >> 7;                      // 0/1
    int half = (tid >> 6) & 1;                // 0: xd, 1: hd (wave-uniform)
    float gc[8], mi[8];
    if (half == 0) {
      float4 a = *(const float4*)(gxd + c8), b = *(const float4*)(gxd + c8 + 4);
      float4 p = *(const float4*)(mimp + c8), q = *(const float4*)(mimp + c8 + 4);
#pragma unroll
      for (int j = 0; j < 4; ++j) {
        gc[j] = -fmaxf(0.f, ((const float*)&a)[j]);
        gc[j + 4] = -fmaxf(0.f, ((const float*)&b)[j]);
        mi[j] = ((const float*)&p)[j];
        mi[j + 4] = ((const float*)&q)[j];
      }
    } else {
      float4 a = *(const float4*)(ghd + c8), b = *(const float4*)(ghd + c8 + 4);
#pragma unroll
      for (int j = 0; j < 4; ++j) {
        gc[j] = -fmaxf(0.f, ((const float*)&a)[j]);
        gc[j + 4] = -fmaxf(0.f, ((const float*)&b)[j]);
      }
    }
    VMC("0");
    barrier_();
#pragma unroll
    for (int u = 0; u < 2; ++u) {
      int row = u * 2 + row2;                 // 0..3
      bf16x8 o;
      if (half == 0) {
        const float* xr = &SHF[row * 1536 + c8];
        float xv[8], mv[8], dv[8];
        *(float4*)&xv[0] = *(const float4*)(xr);
        *(float4*)&xv[4] = *(const float4*)(xr + 4);
        *(float4*)&mv[0] = *(const float4*)(xr + 512);
        *(float4*)&mv[4] = *(const float4*)(xr + 516);
        *(float4*)&dv[0] = *(const float4*)(xr + 1024);
        *(float4*)&dv[4] = *(const float4*)(xr + 1028);
#pragma unroll
        for (int j = 0; j < 8; ++j) {
          float g = __expf(gc[j] * dv[j]);
          float xd = mv[j] * xv[j] + (1.f - mv[j]) * (g * xv[j] + (1.f - g) * mi[j]);
          o[j] = (__bf16)xd;
        }
        *(bf16x8*)(A1 + (size_t)(r0 + row) * 1024 + c8) = o;
      } else {
        const float* dr = &SHF[row * 1536 + 1024 + c8];
        const float* hr = &SHF[6144 + row * 512 + c8];
        float dv[8], hv[8];
        *(float4*)&dv[0] = *(const float4*)(dr);
        *(float4*)&dv[4] = *(const float4*)(dr + 4);
        *(float4*)&hv[0] = *(const float4*)(hr);
        *(float4*)&hv[4] = *(const float4*)(hr + 4);
#pragma unroll
        for (int j = 0; j < 8; ++j) {
          float hd = __expf(gc[j] * dv[j]) * hv[j];
          o[j] = (__bf16)hd;
        }
        *(bf16x8*)(A1 + (size_t)(r0 + row) * 1024 + 512 + c8) = o;
      }
    }
  } else {
    // pack one 64x64 (k,n) tile, transposed, into dst[n][k] (ldk=1024)
    __bf16* Tb = (__bf16*)SHF;                // [64][65] bf16
    int bid = blockIdx.x - 4096;
    const float* S;
    __bf16* dst;
    int tk, tn, nadj;
    if (bid < 256) {           // Wzr: 16 k-tiles x 16 n-tiles
      tk = (bid >> 4) * 64; tn = (bid & 15) * 64;
      bool khi = tk >= 512, nhi = tn >= 512;
      S = nhi ? (khi ? Ur : Wr) : (khi ? Uz : Wz);
      nadj = nhi ? 512 : 0;
      dst = Wzr;
    } else {                   // Wht: 16 k-tiles x 8 n-tiles
      int b2 = bid - 256;
      tk = (b2 >> 3) * 64; tn = (b2 & 7) * 64;
      S = (tk >= 512) ? Uh : Wh;
      nadj = 0;
      dst = Wht;
    }
    int kadj = (tk >= 512) ? 512 : 0;
    int kl = tid >> 4, n4 = (tid & 15) << 2;
#pragma unroll
    for (int rr = 0; rr < 4; ++rr) {
      int k = rr * 16 + kl;
      float4 v = *(const float4*)(S + (size_t)(tk - kadj + k) * 512 + (tn - nadj) + n4);
      Tb[k * 65 + n4 + 0] = (__bf16)v.x;
      Tb[k * 65 + n4 + 1] = (__bf16)v.y;
      Tb[k * 65 + n4 + 2] = (__bf16)v.z;
      Tb[k * 65 + n4 + 3] = (__bf16)v.w;
    }
    __syncthreads();
    int k0 = (tid & 7) * 8;
#pragma unroll
    for (int h = 0; h < 2; ++h) {
      int nl = (tid >> 3) + h * 32;
      bf16x8 v;
#pragma unroll
      for (int i = 0; i < 8; ++i) v[i] = Tb[(k0 + i) * 65 + nl];
      *(bf16x8*)(dst + (size_t)(tn + nl) * 1024 + tk + k0) = v;
    }
  }
}

// ---------------- 2-buffer, TRUE 2-blocks/CU GEMM (BM=128, BK=32) ----------------
// LDS packed layout (16B units): logical element (row m, 16B k-chunk ku in 0..3)
// stored at unit (m>>1)*8 + (((m&1)*4 + ku) ^ ((m>>1)&7)).
// Staging writes linear units; per-lane global source applies the inverse map.

template <int MODE>
__global__ __launch_bounds__(512, 4) void gemm7_k(
    const __bf16* __restrict__ A1, const __bf16* __restrict__ RH,
    const __bf16* __restrict__ Bt,
    __bf16* __restrict__ Zb, __bf16* __restrict__ RHout,
    const float* __restrict__ bza, const float* __restrict__ bzb,
    float* __restrict__ out) {
  constexpr int NI = (MODE == 0) ? 4 : 2;     // n-frags per wave
  constexpr int BN = NI * 64;                 // 256 / 128 (4 wn-waves)
  constexpr int BUNITS = BN * 4;              // B 16B-units per tile
  constexpr int SBUF = 512 + BUNITS;          // A(128 rows)=512 | B
  __shared__ bf16x8 ldsv[2 * SBUF];           // 48KB / 32KB -> 2 blocks/CU
  constexpr int NT = 32;                      // K=1024, BK=32

  int bid = blockIdx.x;
  int swz = (bid & 7) * 64 + (bid >> 3);      // bijective XCD swizzle (512=8x64)
  int bm = swz >> 2, bn = swz & 3;            // 128 x 4
  int tid = threadIdx.x, lane = tid & 63, wid = tid >> 6;
  int wm = wid >> 2, wn = wid & 3;            // 2M x 4N waves: 64 x (NI*16)

  // per-lane staging source offsets (inverse of packed-swizzle map)
  auto inv = [&](int U, int ldb) {
    int r = U >> 3, s = (U & 7) ^ (r & 7);
    return (2 * r + (s >> 2)) * ldb + (s & 3) * 16;  // bytes
  };
  int UA = wid * 64 + lane;                   // A: 512 units, 1 load/wave
  int offA = inv(UA, 2048);
  int offAr = inv(UA, 1024);                  // MODE1 RH half
  int UB0 = (MODE == 0) ? (wid * 128 + lane) : (wid * 64 + lane);
  int offB0 = inv(UB0, 2048);
  int offB1 = (MODE == 0) ? inv(UB0 + 64, 2048) : 0;
  int ldsB = (MODE == 0) ? (wid * 128) : (wid * 64);   // wave-uniform

  auto stage = [&](int t, int buf) {
    const char* gA;
    int oA;
    if (MODE == 0 || t < 16) {
      gA = (const char*)A1 + (size_t)bm * 128 * 2048 + t * 64;
      oA = offA;
    } else {
      gA = (const char*)RH + (size_t)bm * 128 * 1024 + (t - 16) * 64;
      oA = offAr;
    }
    __builtin_amdgcn_global_load_lds((g_vp*)(gA + oA),
        (lds_vp*)(ldsv + buf * SBUF + wid * 64), 16, 0, 0);
    const char* gB = (const char*)Bt + (size_t)bn * BN * 2048 + t * 64;
    __builtin_amdgcn_global_load_lds((g_vp*)(gB + offB0),
        (lds_vp*)(ldsv + buf * SBUF + 512 + ldsB), 16, 0, 0);
    if constexpr (MODE == 0) {
      __builtin_amdgcn_global_load_lds((g_vp*)(gB + offB1),
          (lds_vp*)(ldsv + buf * SBUF + 512 + ldsB + 64), 16, 0, 0);
    }
  };

  // fragment read bases (16B units), loop-invariant
  int lr = (lane & 15) >> 1;
  int lo = ((lane & 1) << 2) | (lane >> 4);
  int aoff = lr * 8 + (lo ^ lr);
  int aB = wm * 256 + aoff;                   // + mf*64
  int bB = 512 + wn * (NI * 64) + aoff;       // + nf*64

  f32x4 acc[4][NI] = {};

  stage(0, 0);
  VMC("0");
  barrier_();

  int cur = 0;
  for (int t = 0; t < NT; ++t) {
    if (t + 1 < NT) stage(t + 1, cur ^ 1);
    int base = cur * SBUF;

    bf16x8 bf[NI];
#pragma unroll
    for (int nf = 0; nf < NI; ++nf) bf[nf] = ldsv[base + bB + nf * 64];
    __builtin_amdgcn_s_setprio(1);
#pragma unroll
    for (int mf = 0; mf < 4; ++mf) {
      bf16x8 a = ldsv[base + aB + mf * 64];
#pragma unroll
      for (int nf = 0; nf < NI; ++nf)
        acc[mf][nf] = __builtin_amdgcn_mfma_f32_16x16x32_bf16(a, bf[nf],
                                                              acc[mf][nf], 0, 0, 0);
    }
    __builtin_amdgcn_s_setprio(0);

    if (t + 1 < NT) {
      VMC("0");     // next-tile stage complete
      barrier_();   // all waves done reading buf[cur]
    }
    cur ^= 1;
  }

  // ---------------- epilogue ----------------
  int col16 = lane & 15, rgrp = lane >> 4;
#pragma unroll
  for (int mf = 0; mf < 4; ++mf) {
    int grow0 = bm * 128 + wm * 64 + mf * 16 + rgrp * 4;
#pragma unroll
    for (int nf = 0; nf < NI; ++nf) {
      int gc = bn * BN + wn * (NI * 16) + nf * 16 + col16;
      if constexpr (MODE == 0) {
        if (gc < 512) {  // z columns (block-uniform: BN=256, bn<2)
          float b = bza[gc];
#pragma unroll
          for (int j = 0; j < 4; ++j) {
            float z = sigmoidf_(acc[mf][nf][j] + b);
            Zb[(size_t)(grow0 + j) * 512 + gc] = (__bf16)z;
          }
        } else {       // r columns
          int c = gc - 512;
          float b = bzb[c];
#pragma unroll
          for (int j = 0; j < 4; ++j) {
            int grow = grow0 + j;
            float r = sigmoidf_(acc[mf][nf][j] + b);
            float hd = (float)A1[(size_t)grow * 1024 + 512 + c];
            RHout[(size_t)grow * 512 + c] = (__bf16)(r * hd);
          }
        }
      } else {
        float b = bza[gc];
#pragma unroll
        for (int j = 0; j < 4; ++j) {
          int grow = grow0 + j;
          float hh = tanhf(acc[mf][nf][j] + b);
          float hd = (float)A1[(size_t)grow * 1024 + 512 + gc];
          float z = (float)Zb[(size_t)grow * 512 + gc];
          out[(size_t)grow * 512 + gc] = (1.f - z) * hd + z * hh;
        }
      }
    }
  }
}

// ---------------- launch ----------------
extern "C" void kernel_launch(void* const* d_in, const int* in_sizes, int n_in,
                              void* d_out, int out_size, void* d_ws, size_t ws_size,
                              hipStream_t stream) {
  const float* inputs = (const float*)d_in[0];
  const float* h_prev = (const float*)d_in[1];
  const float* W_z = (const float*)d_in[2];
  const float* U_z = (const float*)d_in[3];
  const float* b_z = (const float*)d_in[4];
  const float* W_r = (const float*)d_in[5];
  const float* U_r = (const float*)d_in[6];
  const float* b_r = (const float*)d_in[7];
  const float* W_h = (const float*)d_in[8];
  const float* U_h = (const float*)d_in[9];
  const float* b_h = (const float*)d_in[10];
  const float* gxd = (const float*)d_in[11];
  const float* ghd = (const float*)d_in[12];
  const float* mimp = (const float*)d_in[13];
  float* out = (float*)d_out;

  char* ws = (char*)d_ws;
  __bf16* A1  = (__bf16*)(ws);                  // 16384x1024 bf16 = 32MB
  __bf16* RH  = (__bf16*)(ws + 33554432);       // 16384x512 bf16 = 16MB
  __bf16* Zb  = (__bf16*)(ws + 50331648);       // 16384x512 bf16 = 16MB
  __bf16* Wzr = (__bf16*)(ws + 67108864);       // 1024x1024 bf16 = 2MB
  __bf16* Wht = (__bf16*)(ws + 69206016);       // 512x1024 bf16  = 1MB

  prep_pack_k<<<4480, 256, 0, stream>>>(inputs, h_prev, gxd, ghd, mimp, A1,
                                        W_z, U_z, W_r, U_r, W_h, U_h, Wzr, Wht);
  gemm7_k<0><<<512, 512, 0, stream>>>(A1, RH, Wzr, Zb, RH, b_z, b_r, nullptr);
  gemm7_k<1><<<512, 512, 0, stream>>>(A1, RH, Wht, Zb, nullptr, b_h, nullptr, out);
}

// Round 17
// 111.267 us; speedup vs baseline: 1.1124x; 1.0496x over previous
//
#include <hip/hip_runtime.h>
#include <cmath>

// GRU-D cell: B=16384, F=U=512.
//   prep_pack: xd,hd -> A1=[xd|hd] bf16 (B x 1024); weights -> bf16 B^T
//   gemm7<0>: A1 @ Wzr -> sigmoid -> Zb (bf16), RH = r*hd (bf16)  [128x256, BK=32]
//   gemm8:    [xd|RH] @ Wht -> tanh, blend, out                    [128x128, BK=64]
// R17: gemm1-only BK 32->64 (NT 32->16): halves its barrier+vmcnt events at
// unchanged 2 blocks/CU (LDS 64KB). Evidence: gemm1 at half gemm0's FLOPs
// has cost ~= gemm0 across all rounds -> fixed-cost-per-tile bound.
// gemm7<0> + prep_pack byte-identical to R16 (passed, 116.8 total).

typedef __bf16 bf16x8 __attribute__((ext_vector_type(8)));
typedef __bf16 bf16x4 __attribute__((ext_vector_type(4)));
typedef float f32x4 __attribute__((ext_vector_type(4)));

typedef __attribute__((address_space(3))) void lds_vp;
typedef const __attribute__((address_space(1))) void g_vp;

#define VMC(N) asm volatile("s_waitcnt vmcnt(" N ")" ::: "memory")

__device__ __forceinline__ void barrier_() {
  asm volatile("" ::: "memory");
  __builtin_amdgcn_s_barrier();
  asm volatile("" ::: "memory");
}

__device__ __forceinline__ float sigmoidf_(float x) { return 1.f / (1.f + expf(-x)); }

// ---------------- prep (global_load_lds staged) + pack (LDS transpose) ----------------
__global__ __launch_bounds__(256) void prep_pack_k(
    const float* __restrict__ inp, const float* __restrict__ h_prev,
    const float* __restrict__ gxd, const float* __restrict__ ghd,
    const float* __restrict__ mimp, __bf16* __restrict__ A1,
    const float* __restrict__ Wz, const float* __restrict__ Uz,
    const float* __restrict__ Wr, const float* __restrict__ Ur,
    const float* __restrict__ Wh, const float* __restrict__ Uh,
    __bf16* __restrict__ Wzr, __bf16* __restrict__ Wht) {
  __shared__ __align__(16) float SHF[8192];   // 32KB, aliased by pack branch
  int tid = threadIdx.x;
  int lane = tid & 63, wid = tid >> 6;
  if (blockIdx.x < 4096) {
    int r0 = blockIdx.x * 4;                  // 4 rows per block
    const char* gi = (const char*)(inp + (size_t)r0 * 1536);
    const char* gh = (const char*)(h_prev + (size_t)r0 * 512);
#pragma unroll
    for (int i = 0; i < 6; ++i) {
      int seg = i * 4 + wid;                  // 1KB segment
      __builtin_amdgcn_global_load_lds((g_vp*)(gi + seg * 1024 + lane * 16),
                                       (lds_vp*)((char*)SHF + seg * 1024), 16, 0, 0);
    }
#pragma unroll
    for (int i = 0; i < 2; ++i) {
      int seg = i * 4 + wid;
      __builtin_amdgcn_global_load_lds((g_vp*)(gh + seg * 1024 + lane * 16),
                                       (lds_vp*)((char*)SHF + 24576 + seg * 1024), 16, 0, 0);
    }
    int c8 = (tid & 63) << 3;
    int row2 = tid >> 7;                      // 0/1
    int half = (tid >> 6) & 1;                // 0: xd, 1: hd (wave-uniform)
    float gc[8], mi[8];
    if (half == 0) {
      float4 a = *(const float4*)(gxd + c8), b = *(const float4*)(gxd + c8 + 4);
      float4 p = *(const float4*)(mimp + c8), q = *(const float4*)(mimp + c8 + 4);
#pragma unroll
      for (int j = 0; j < 4; ++j) {
        gc[j] = -fmaxf(0.f, ((const float*)&a)[j]);
        gc[j + 4] = -fmaxf(0.f, ((const float*)&b)[j]);
        mi[j] = ((const float*)&p)[j];
        mi[j + 4] = ((const float*)&q)[j];
      }
    } else {
      float4 a = *(const float4*)(ghd + c8), b = *(const float4*)(ghd + c8 + 4);
#pragma unroll
      for (int j = 0; j < 4; ++j) {
        gc[j] = -fmaxf(0.f, ((const float*)&a)[j]);
        gc[j + 4] = -fmaxf(0.f, ((const float*)&b)[j]);
      }
    }
    VMC("0");
    barrier_();
#pragma unroll
    for (int u = 0; u < 2; ++u) {
      int row = u * 2 + row2;                 // 0..3
      bf16x8 o;
      if (half == 0) {
        const float* xr = &SHF[row * 1536 + c8];
        float xv[8], mv[8], dv[8];
        *(float4*)&xv[0] = *(const float4*)(xr);
        *(float4*)&xv[4] = *(const float4*)(xr + 4);
        *(float4*)&mv[0] = *(const float4*)(xr + 512);
        *(float4*)&mv[4] = *(const float4*)(xr + 516);
        *(float4*)&dv[0] = *(const float4*)(xr + 1024);
        *(float4*)&dv[4] = *(const float4*)(xr + 1028);
#pragma unroll
        for (int j = 0; j < 8; ++j) {
          float g = __expf(gc[j] * dv[j]);
          float xd = mv[j] * xv[j] + (1.f - mv[j]) * (g * xv[j] + (1.f - g) * mi[j]);
          o[j] = (__bf16)xd;
        }
        *(bf16x8*)(A1 + (size_t)(r0 + row) * 1024 + c8) = o;
      } else {
        const float* dr = &SHF[row * 1536 + 1024 + c8];
        const float* hr = &SHF[6144 + row * 512 + c8];
        float dv[8], hv[8];
        *(float4*)&dv[0] = *(const float4*)(dr);
        *(float4*)&dv[4] = *(const float4*)(dr + 4);
        *(float4*)&hv[0] = *(const float4*)(hr);
        *(float4*)&hv[4] = *(const float4*)(hr + 4);
#pragma unroll
        for (int j = 0; j < 8; ++j) {
          float hd = __expf(gc[j] * dv[j]) * hv[j];
          o[j] = (__bf16)hd;
        }
        *(bf16x8*)(A1 + (size_t)(r0 + row) * 1024 + 512 + c8) = o;
      }
    }
  } else {
    // pack one 64x64 (k,n) tile, transposed, into dst[n][k] (ldk=1024)
    __bf16* Tb = (__bf16*)SHF;                // [64][65] bf16
    int bid = blockIdx.x - 4096;
    const float* S;
    __bf16* dst;
    int tk, tn, nadj;
    if (bid < 256) {           // Wzr: 16 k-tiles x 16 n-tiles
      tk = (bid >> 4) * 64; tn = (bid & 15) * 64;
      bool khi = tk >= 512, nhi = tn >= 512;
      S = nhi ? (khi ? Ur : Wr) : (khi ? Uz : Wz);
      nadj = nhi ? 512 : 0;
      dst = Wzr;
    } else {                   // Wht: 16 k-tiles x 8 n-tiles
      int b2 = bid - 256;
      tk = (b2 >> 3) * 64; tn = (b2 & 7) * 64;
      S = (tk >= 512) ? Uh : Wh;
      nadj = 0;
      dst = Wht;
    }
    int kadj = (tk >= 512) ? 512 : 0;
    int kl = tid >> 4, n4 = (tid & 15) << 2;
#pragma unroll
    for (int rr = 0; rr < 4; ++rr) {
      int k = rr * 16 + kl;
      float4 v = *(const float4*)(S + (size_t)(tk - kadj + k) * 512 + (tn - nadj) + n4);
      Tb[k * 65 + n4 + 0] = (__bf16)v.x;
      Tb[k * 65 + n4 + 1] = (__bf16)v.y;
      Tb[k * 65 + n4 + 2] = (__bf16)v.z;
      Tb[k * 65 + n4 + 3] = (__bf16)v.w;
    }
    __syncthreads();
    int k0 = (tid & 7) * 8;
#pragma unroll
    for (int h = 0; h < 2; ++h) {
      int nl = (tid >> 3) + h * 32;
      bf16x8 v;
#pragma unroll
      for (int i = 0; i < 8; ++i) v[i] = Tb[(k0 + i) * 65 + nl];
      *(bf16x8*)(dst + (size_t)(tn + nl) * 1024 + tk + k0) = v;
    }
  }
}

// ---------------- gemm7: 2-buffer 2-blocks/CU (BM=128, BK=32) -- MODE0 ----------------
// LDS packed layout (16B units): logical element (row m, 16B k-chunk ku in 0..3)
// stored at unit (m>>1)*8 + (((m&1)*4 + ku) ^ ((m>>1)&7)).
template <int MODE>
__global__ __launch_bounds__(512, 4) void gemm7_k(
    const __bf16* __restrict__ A1, const __bf16* __restrict__ RH,
    const __bf16* __restrict__ Bt,
    __bf16* __restrict__ Zb, __bf16* __restrict__ RHout,
    const float* __restrict__ bza, const float* __restrict__ bzb,
    float* __restrict__ out) {
  constexpr int NI = (MODE == 0) ? 4 : 2;     // n-frags per wave
  constexpr int BN = NI * 64;                 // 256 / 128 (4 wn-waves)
  constexpr int BUNITS = BN * 4;              // B 16B-units per tile
  constexpr int SBUF = 512 + BUNITS;          // A(128 rows)=512 | B
  __shared__ bf16x8 ldsv[2 * SBUF];           // 48KB / 32KB -> 2 blocks/CU
  constexpr int NT = 32;                      // K=1024, BK=32

  int bid = blockIdx.x;
  int swz = (bid & 7) * 64 + (bid >> 3);      // bijective XCD swizzle (512=8x64)
  int bm = swz >> 2, bn = swz & 3;            // 128 x 4
  int tid = threadIdx.x, lane = tid & 63, wid = tid >> 6;
  int wm = wid >> 2, wn = wid & 3;            // 2M x 4N waves: 64 x (NI*16)

  auto inv = [&](int U, int ldb) {
    int r = U >> 3, s = (U & 7) ^ (r & 7);
    return (2 * r + (s >> 2)) * ldb + (s & 3) * 16;  // bytes
  };
  int UA = wid * 64 + lane;                   // A: 512 units, 1 load/wave
  int offA = inv(UA, 2048);
  int offAr = inv(UA, 1024);                  // MODE1 RH half
  int UB0 = (MODE == 0) ? (wid * 128 + lane) : (wid * 64 + lane);
  int offB0 = inv(UB0, 2048);
  int offB1 = (MODE == 0) ? inv(UB0 + 64, 2048) : 0;
  int ldsB = (MODE == 0) ? (wid * 128) : (wid * 64);   // wave-uniform

  auto stage = [&](int t, int buf) {
    const char* gA;
    int oA;
    if (MODE == 0 || t < 16) {
      gA = (const char*)A1 + (size_t)bm * 128 * 2048 + t * 64;
      oA = offA;
    } else {
      gA = (const char*)RH + (size_t)bm * 128 * 1024 + (t - 16) * 64;
      oA = offAr;
    }
    __builtin_amdgcn_global_load_lds((g_vp*)(gA + oA),
        (lds_vp*)(ldsv + buf * SBUF + wid * 64), 16, 0, 0);
    const char* gB = (const char*)Bt + (size_t)bn * BN * 2048 + t * 64;
    __builtin_amdgcn_global_load_lds((g_vp*)(gB + offB0),
        (lds_vp*)(ldsv + buf * SBUF + 512 + ldsB), 16, 0, 0);
    if constexpr (MODE == 0) {
      __builtin_amdgcn_global_load_lds((g_vp*)(gB + offB1),
          (lds_vp*)(ldsv + buf * SBUF + 512 + ldsB + 64), 16, 0, 0);
    }
  };

  int lr = (lane & 15) >> 1;
  int lo = ((lane & 1) << 2) | (lane >> 4);
  int aoff = lr * 8 + (lo ^ lr);
  int aB = wm * 256 + aoff;                   // + mf*64
  int bB = 512 + wn * (NI * 64) + aoff;       // + nf*64

  f32x4 acc[4][NI] = {};

  stage(0, 0);
  VMC("0");
  barrier_();

  int cur = 0;
  for (int t = 0; t < NT; ++t) {
    if (t + 1 < NT) stage(t + 1, cur ^ 1);
    int base = cur * SBUF;

    bf16x8 bf[NI];
#pragma unroll
    for (int nf = 0; nf < NI; ++nf) bf[nf] = ldsv[base + bB + nf * 64];
    __builtin_amdgcn_s_setprio(1);
#pragma unroll
    for (int mf = 0; mf < 4; ++mf) {
      bf16x8 a = ldsv[base + aB + mf * 64];
#pragma unroll
      for (int nf = 0; nf < NI; ++nf)
        acc[mf][nf] = __builtin_amdgcn_mfma_f32_16x16x32_bf16(a, bf[nf],
                                                              acc[mf][nf], 0, 0, 0);
    }
    __builtin_amdgcn_s_setprio(0);

    if (t + 1 < NT) {
      VMC("0");
      barrier_();
    }
    cur ^= 1;
  }

  int col16 = lane & 15, rgrp = lane >> 4;
#pragma unroll
  for (int mf = 0; mf < 4; ++mf) {
    int grow0 = bm * 128 + wm * 64 + mf * 16 + rgrp * 4;
#pragma unroll
    for (int nf = 0; nf < NI; ++nf) {
      int gc = bn * BN + wn * (NI * 16) + nf * 16 + col16;
      if constexpr (MODE == 0) {
        if (gc < 512) {
          float b = bza[gc];
#pragma unroll
          for (int j = 0; j < 4; ++j) {
            float z = sigmoidf_(acc[mf][nf][j] + b);
            Zb[(size_t)(grow0 + j) * 512 + gc] = (__bf16)z;
          }
        } else {
          int c = gc - 512;
          float b = bzb[c];
#pragma unroll
          for (int j = 0; j < 4; ++j) {
            int grow = grow0 + j;
            float r = sigmoidf_(acc[mf][nf][j] + b);
            float hd = (float)A1[(size_t)grow * 1024 + 512 + c];
            RHout[(size_t)grow * 512 + c] = (__bf16)(r * hd);
          }
        }
      } else {
        float b = bza[gc];
#pragma unroll
        for (int j = 0; j < 4; ++j) {
          int grow = grow0 + j;
          float hh = tanhf(acc[mf][nf][j] + b);
          float hd = (float)A1[(size_t)grow * 1024 + 512 + gc];
          float z = (float)Zb[(size_t)grow * 512 + gc];
          out[(size_t)grow * 512 + gc] = (1.f - z) * hd + z * hh;
        }
      }
    }
  }
}

// ---------------- gemm8: gemm1 with BK=64, NT=16 (half the sync events) ----------------
// LDS layout (16B units): (row m, chunk ku in 0..7) at unit m*8 + (ku ^ (m&7)).
// Bank check: 8 distinct bank-groups per 8 rows -> 2-way alias (free).
__global__ __launch_bounds__(512, 4) void gemm8_k(
    const __bf16* __restrict__ A1, const __bf16* __restrict__ RH,
    const __bf16* __restrict__ Bt,
    const __bf16* __restrict__ Zb, const float* __restrict__ bh,
    float* __restrict__ out) {
  constexpr int SBUF = 2048;                  // A 1024 | B 1024 units
  __shared__ bf16x8 ldsv[2 * SBUF];           // 64KB -> 2 blocks/CU
  constexpr int NT = 16;                      // K=1024, BK=64

  int bid = blockIdx.x;
  int swz = (bid & 7) * 64 + (bid >> 3);      // bijective XCD swizzle (512=8x64)
  int bm = swz >> 2, bn = swz & 3;            // 128 x 4
  int tid = threadIdx.x, lane = tid & 63, wid = tid >> 6;
  int wm = wid >> 2, wn = wid & 3;            // 2M x 4N waves: 64 x 32

  // staging: U = wid*128 + i*64 + lane; row=U>>3, kc=(U&7)^(row&7)
  int U0 = wid * 128 + lane, U1 = U0 + 64;
  auto srcoff = [&](int U, int ldb) {
    int r = U >> 3;
    return r * ldb + (((U & 7) ^ (r & 7)) << 4);   // bytes
  };
  int oA0x = srcoff(U0, 2048), oA1x = srcoff(U1, 2048);  // A1 (xd, t<8)
  int oA0r = srcoff(U0, 1024), oA1r = srcoff(U1, 1024);  // RH  (t>=8)
  int oB0 = srcoff(U0, 2048), oB1 = srcoff(U1, 2048);

  auto stage = [&](int t, int buf) {
    const char* gA;
    int a0, a1;
    if (t < 8) {
      gA = (const char*)A1 + (size_t)bm * 128 * 2048 + t * 128;
      a0 = oA0x; a1 = oA1x;
    } else {
      gA = (const char*)RH + (size_t)bm * 128 * 1024 + (t - 8) * 128;
      a0 = oA0r; a1 = oA1r;
    }
    __builtin_amdgcn_global_load_lds((g_vp*)(gA + a0),
        (lds_vp*)(ldsv + buf * SBUF + wid * 128), 16, 0, 0);
    __builtin_amdgcn_global_load_lds((g_vp*)(gA + a1),
        (lds_vp*)(ldsv + buf * SBUF + wid * 128 + 64), 16, 0, 0);
    const char* gB = (const char*)Bt + (size_t)bn * 128 * 2048 + t * 128;
    __builtin_amdgcn_global_load_lds((g_vp*)(gB + oB0),
        (lds_vp*)(ldsv + buf * SBUF + 1024 + wid * 128), 16, 0, 0);
    __builtin_amdgcn_global_load_lds((g_vp*)(gB + oB1),
        (lds_vp*)(ldsv + buf * SBUF + 1024 + wid * 128 + 64), 16, 0, 0);
  };

  // fragment reads: row_a = wm*64 + mf*16 + (lane&15); ku = kk*4 + (lane>>4)
  int hi = lane >> 4;
  int ra = wm * 64 + (lane & 15);             // + mf*16
  int rb = wn * 32 + (lane & 15);             // + nf*16
  int sa = ra & 7, sb = rb & 7;               // const across mf/nf (16-stride)

  f32x4 acc[4][2] = {};

  stage(0, 0);
  VMC("0");
  barrier_();

  int cur = 0;
  for (int t = 0; t < NT; ++t) {
    if (t + 1 < NT) stage(t + 1, cur ^ 1);
    int base = cur * SBUF;

    __builtin_amdgcn_s_setprio(1);
#pragma unroll
    for (int kk = 0; kk < 2; ++kk) {
      int ku = kk * 4 + hi;
      bf16x8 bf[2];
#pragma unroll
      for (int nf = 0; nf < 2; ++nf)
        bf[nf] = ldsv[base + 1024 + (rb + nf * 16) * 8 + (ku ^ sb)];
#pragma unroll
      for (int mf = 0; mf < 4; ++mf) {
        bf16x8 a = ldsv[base + (ra + mf * 16) * 8 + (ku ^ sa)];
#pragma unroll
        for (int nf = 0; nf < 2; ++nf)
          acc[mf][nf] = __builtin_amdgcn_mfma_f32_16x16x32_bf16(a, bf[nf],
                                                                acc[mf][nf], 0, 0, 0);
      }
    }
    __builtin_amdgcn_s_setprio(0);

    if (t + 1 < NT) {
      VMC("0");
      barrier_();
    }
    cur ^= 1;
  }

  int col16 = lane & 15, rgrp = lane >> 4;
#pragma unroll
  for (int mf = 0; mf < 4; ++mf) {
    int grow0 = bm * 128 + wm * 64 + mf * 16 + rgrp * 4;
#pragma unroll
    for (int nf = 0; nf < 2; ++nf) {
      int gc = bn * 128 + wn * 32 + nf * 16 + col16;
      float b = bh[gc];
#pragma unroll
      for (int j = 0; j < 4; ++j) {
        int grow = grow0 + j;
        float hh = tanhf(acc[mf][nf][j] + b);
        float hd = (float)A1[(size_t)grow * 1024 + 512 + gc];
        float z = (float)Zb[(size_t)grow * 512 + gc];
        out[(size_t)grow * 512 + gc] = (1.f - z) * hd + z * hh;
      }
    }
  }
}

// ---------------- launch ----------------
extern "C" void kernel_launch(void* const* d_in, const int* in_sizes, int n_in,
                              void* d_out, int out_size, void* d_ws, size_t ws_size,
                              hipStream_t stream) {
  const float* inputs = (const float*)d_in[0];
  const float* h_prev = (const float*)d_in[1];
  const float* W_z = (const float*)d_in[2];
  const float* U_z = (const float*)d_in[3];
  const float* b_z = (const float*)d_in[4];
  const float* W_r = (const float*)d_in[5];
  const float* U_r = (const float*)d_in[6];
  const float* b_r = (const float*)d_in[7];
  const float* W_h = (const float*)d_in[8];
  const float* U_h = (const float*)d_in[9];
  const float* b_h = (const float*)d_in[10];
  const float* gxd = (const float*)d_in[11];
  const float* ghd = (const float*)d_in[12];
  const float* mimp = (const float*)d_in[13];
  float* out = (float*)d_out;

  char* ws = (char*)d_ws;
  __bf16* A1  = (__bf16*)(ws);                  // 16384x1024 bf16 = 32MB
  __bf16* RH  = (__bf16*)(ws + 33554432);       // 16384x512 bf16 = 16MB
  __bf16* Zb  = (__bf16*)(ws + 50331648);       // 16384x512 bf16 = 16MB
  __bf16* Wzr = (__bf16*)(ws + 67108864);       // 1024x1024 bf16 = 2MB
  __bf16* Wht = (__bf16*)(ws + 69206016);       // 512x1024 bf16  = 1MB

  prep_pack_k<<<4480, 256, 0, stream>>>(inputs, h_prev, gxd, ghd, mimp, A1,
                                        W_z, U_z, W_r, U_r, W_h, U_h, Wzr, Wht);
  gemm7_k<0><<<512, 512, 0, stream>>>(A1, RH, Wzr, Zb, RH, b_z, b_r, nullptr);
  gemm8_k<<<512, 512, 0, stream>>>(A1, RH, Wht, Zb, b_h, out);
}

// Round 18
// 111.251 us; speedup vs baseline: 1.1126x; 1.0001x over previous
//
#include <hip/hip_runtime.h>
#include <cmath>

// GRU-D cell: B=16384, F=U=512.
//   prep_pack: xd,hd -> A1=[xd|hd] bf16 (B x 1024); weights -> bf16 B^T
//   gemm9: A1 @ Wzr -> sigmoid -> Zb (bf16), RH = r*hd   [256x256, BK=64, grid 256]
//   gemm8: [xd|RH] @ Wht -> tanh, blend, out             [128x128, BK=64, grid 512]
// R18: gemm0 gets the R17 mechanism at max block size: BM=BN=256, BK=64 ->
// tiles/CU 64 -> 16 (4x fewer sync events; each tile = fixed latency-drain
// + 2 barriers). LDS 128KB, 1 blk/CU -- trade co-residency (R16: ~-3us)
// for 4x sync cut (R17: 2x cut on lighter gemm = -5.5us).
// gemm8 + prep_pack byte-identical to R17 (passed, 111.3 total).

typedef __bf16 bf16x8 __attribute__((ext_vector_type(8)));
typedef __bf16 bf16x4 __attribute__((ext_vector_type(4)));
typedef float f32x4 __attribute__((ext_vector_type(4)));

typedef __attribute__((address_space(3))) void lds_vp;
typedef const __attribute__((address_space(1))) void g_vp;

#define VMC(N) asm volatile("s_waitcnt vmcnt(" N ")" ::: "memory")

__device__ __forceinline__ void barrier_() {
  asm volatile("" ::: "memory");
  __builtin_amdgcn_s_barrier();
  asm volatile("" ::: "memory");
}

__device__ __forceinline__ float sigmoidf_(float x) { return 1.f / (1.f + expf(-x)); }

// ---------------- prep (global_load_lds staged) + pack (LDS transpose) ----------------
__global__ __launch_bounds__(256) void prep_pack_k(
    const float* __restrict__ inp, const float* __restrict__ h_prev,
    const float* __restrict__ gxd, const float* __restrict__ ghd,
    const float* __restrict__ mimp, __bf16* __restrict__ A1,
    const float* __restrict__ Wz, const float* __restrict__ Uz,
    const float* __restrict__ Wr, const float* __restrict__ Ur,
    const float* __restrict__ Wh, const float* __restrict__ Uh,
    __bf16* __restrict__ Wzr, __bf16* __restrict__ Wht) {
  __shared__ __align__(16) float SHF[8192];   // 32KB, aliased by pack branch
  int tid = threadIdx.x;
  int lane = tid & 63, wid = tid >> 6;
  if (blockIdx.x < 4096) {
    int r0 = blockIdx.x * 4;                  // 4 rows per block
    const char* gi = (const char*)(inp + (size_t)r0 * 1536);
    const char* gh = (const char*)(h_prev + (size_t)r0 * 512);
#pragma unroll
    for (int i = 0; i < 6; ++i) {
      int seg = i * 4 + wid;                  // 1KB segment
      __builtin_amdgcn_global_load_lds((g_vp*)(gi + seg * 1024 + lane * 16),
                                       (lds_vp*)((char*)SHF + seg * 1024), 16, 0, 0);
    }
#pragma unroll
    for (int i = 0; i < 2; ++i) {
      int seg = i * 4 + wid;
      __builtin_amdgcn_global_load_lds((g_vp*)(gh + seg * 1024 + lane * 16),
                                       (lds_vp*)((char*)SHF + 24576 + seg * 1024), 16, 0, 0);
    }
    int c8 = (tid & 63) << 3;
    int row2 = tid >> 7;                      // 0/1
    int half = (tid >> 6) & 1;                // 0: xd, 1: hd (wave-uniform)
    float gc[8], mi[8];
    if (half == 0) {
      float4 a = *(const float4*)(gxd + c8), b = *(const float4*)(gxd + c8 + 4);
      float4 p = *(const float4*)(mimp + c8), q = *(const float4*)(mimp + c8 + 4);
#pragma unroll
      for (int j = 0; j < 4; ++j) {
        gc[j] = -fmaxf(0.f, ((const float*)&a)[j]);
        gc[j + 4] = -fmaxf(0.f, ((const float*)&b)[j]);
        mi[j] = ((const float*)&p)[j];
        mi[j + 4] = ((const float*)&q)[j];
      }
    } else {
      float4 a = *(const float4*)(ghd + c8), b = *(const float4*)(ghd + c8 + 4);
#pragma unroll
      for (int j = 0; j < 4; ++j) {
        gc[j] = -fmaxf(0.f, ((const float*)&a)[j]);
        gc[j + 4] = -fmaxf(0.f, ((const float*)&b)[j]);
      }
    }
    VMC("0");
    barrier_();
#pragma unroll
    for (int u = 0; u < 2; ++u) {
      int row = u * 2 + row2;                 // 0..3
      bf16x8 o;
      if (half == 0) {
        const float* xr = &SHF[row * 1536 + c8];
        float xv[8], mv[8], dv[8];
        *(float4*)&xv[0] = *(const float4*)(xr);
        *(float4*)&xv[4] = *(const float4*)(xr + 4);
        *(float4*)&mv[0] = *(const float4*)(xr + 512);
        *(float4*)&mv[4] = *(const float4*)(xr + 516);
        *(float4*)&dv[0] = *(const float4*)(xr + 1024);
        *(float4*)&dv[4] = *(const float4*)(xr + 1028);
#pragma unroll
        for (int j = 0; j < 8; ++j) {
          float g = __expf(gc[j] * dv[j]);
          float xd = mv[j] * xv[j] + (1.f - mv[j]) * (g * xv[j] + (1.f - g) * mi[j]);
          o[j] = (__bf16)xd;
        }
        *(bf16x8*)(A1 + (size_t)(r0 + row) * 1024 + c8) = o;
      } else {
        const float* dr = &SHF[row * 1536 + 1024 + c8];
        const float* hr = &SHF[6144 + row * 512 + c8];
        float dv[8], hv[8];
        *(float4*)&dv[0] = *(const float4*)(dr);
        *(float4*)&dv[4] = *(const float4*)(dr + 4);
        *(float4*)&hv[0] = *(const float4*)(hr);
        *(float4*)&hv[4] = *(const float4*)(hr + 4);
#pragma unroll
        for (int j = 0; j < 8; ++j) {
          float hd = __expf(gc[j] * dv[j]) * hv[j];
          o[j] = (__bf16)hd;
        }
        *(bf16x8*)(A1 + (size_t)(r0 + row) * 1024 + 512 + c8) = o;
      }
    }
  } else {
    // pack one 64x64 (k,n) tile, transposed, into dst[n][k] (ldk=1024)
    __bf16* Tb = (__bf16*)SHF;                // [64][65] bf16
    int bid = blockIdx.x - 4096;
    const float* S;
    __bf16* dst;
    int tk, tn, nadj;
    if (bid < 256) {           // Wzr: 16 k-tiles x 16 n-tiles
      tk = (bid >> 4) * 64; tn = (bid & 15) * 64;
      bool khi = tk >= 512, nhi = tn >= 512;
      S = nhi ? (khi ? Ur : Wr) : (khi ? Uz : Wz);
      nadj = nhi ? 512 : 0;
      dst = Wzr;
    } else {                   // Wht: 16 k-tiles x 8 n-tiles
      int b2 = bid - 256;
      tk = (b2 >> 3) * 64; tn = (b2 & 7) * 64;
      S = (tk >= 512) ? Uh : Wh;
      nadj = 0;
      dst = Wht;
    }
    int kadj = (tk >= 512) ? 512 : 0;
    int kl = tid >> 4, n4 = (tid & 15) << 2;
#pragma unroll
    for (int rr = 0; rr < 4; ++rr) {
      int k = rr * 16 + kl;
      float4 v = *(const float4*)(S + (size_t)(tk - kadj + k) * 512 + (tn - nadj) + n4);
      Tb[k * 65 + n4 + 0] = (__bf16)v.x;
      Tb[k * 65 + n4 + 1] = (__bf16)v.y;
      Tb[k * 65 + n4 + 2] = (__bf16)v.z;
      Tb[k * 65 + n4 + 3] = (__bf16)v.w;
    }
    __syncthreads();
    int k0 = (tid & 7) * 8;
#pragma unroll
    for (int h = 0; h < 2; ++h) {
      int nl = (tid >> 3) + h * 32;
      bf16x8 v;
#pragma unroll
      for (int i = 0; i < 8; ++i) v[i] = Tb[(k0 + i) * 65 + nl];
      *(bf16x8*)(dst + (size_t)(tn + nl) * 1024 + tk + k0) = v;
    }
  }
}

// ---------------- gemm9: gemm0 at BM=BN=256, BK=64, grid 256 ----------------
// LDS layout (16B units): (row m, chunk ku in 0..7) at unit m*8 + (ku ^ (m&7)).
// 8 waves 2Mx4N: wave tile 128x64; 64 MFMA/tile; NT=16; 2 buffers (128KB).
__global__ __launch_bounds__(512, 2) void gemm9_k(
    const __bf16* __restrict__ A1, const __bf16* __restrict__ Bt,
    __bf16* __restrict__ Zb, __bf16* __restrict__ RHout,
    const float* __restrict__ bz, const float* __restrict__ br) {
  constexpr int SBUF = 4096;                  // A 2048 | B 2048 units
  __shared__ bf16x8 ldsv[2 * SBUF];           // 128KB -> 1 block/CU
  constexpr int NT = 16;                      // K=1024, BK=64

  int bid = blockIdx.x;
  int swz = (bid & 7) * 32 + (bid >> 3);      // bijective XCD swizzle (256=8x32)
  int bm = swz >> 2, bn = swz & 3;            // 64 x 4
  int tid = threadIdx.x, lane = tid & 63, wid = tid >> 6;
  int wm = wid >> 2, wn = wid & 3;            // wave tile 128 x 64

  // staging: U = wid*256 + i*64 + lane; row=U>>3, kc=(U&7)^(row&7)
  auto srcoff = [&](int U) {
    int r = U >> 3;
    return r * 2048 + (((U & 7) ^ (r & 7)) << 4);   // bytes (ldb=2048)
  };
  int oA[4], oB[4];
#pragma unroll
  for (int i = 0; i < 4; ++i) {
    int U = wid * 256 + i * 64 + lane;
    oA[i] = srcoff(U);
    oB[i] = srcoff(U);
  }

  auto stage = [&](int t, int buf) {
    const char* gA = (const char*)A1 + (size_t)bm * 256 * 2048 + t * 128;
    const char* gB = (const char*)Bt + (size_t)bn * 256 * 2048 + t * 128;
#pragma unroll
    for (int i = 0; i < 4; ++i)
      __builtin_amdgcn_global_load_lds((g_vp*)(gA + oA[i]),
          (lds_vp*)(ldsv + buf * SBUF + wid * 256 + i * 64), 16, 0, 0);
#pragma unroll
    for (int i = 0; i < 4; ++i)
      __builtin_amdgcn_global_load_lds((g_vp*)(gB + oB[i]),
          (lds_vp*)(ldsv + buf * SBUF + 2048 + wid * 256 + i * 64), 16, 0, 0);
  };

  // fragment reads: row_a = wm*128 + mf*16 + (lane&15); ku = kk*4 + (lane>>4)
  int hi = lane >> 4;
  int ra = wm * 128 + (lane & 15);            // + mf*16
  int rb = wn * 64 + (lane & 15);             // + nf*16
  int sa = ra & 7, sb = rb & 7;               // const across mf/nf (16-stride)

  f32x4 acc[8][4] = {};

  stage(0, 0);
  VMC("0");
  barrier_();

  int cur = 0;
  for (int t = 0; t < NT; ++t) {
    if (t + 1 < NT) stage(t + 1, cur ^ 1);
    int base = cur * SBUF;

    __builtin_amdgcn_s_setprio(1);
#pragma unroll
    for (int kk = 0; kk < 2; ++kk) {
      int ku = kk * 4 + hi;
      bf16x8 bf[4];
#pragma unroll
      for (int nf = 0; nf < 4; ++nf)
        bf[nf] = ldsv[base + 2048 + (rb + nf * 16) * 8 + (ku ^ sb)];
#pragma unroll
      for (int mf = 0; mf < 8; ++mf) {
        bf16x8 a = ldsv[base + (ra + mf * 16) * 8 + (ku ^ sa)];
#pragma unroll
        for (int nf = 0; nf < 4; ++nf)
          acc[mf][nf] = __builtin_amdgcn_mfma_f32_16x16x32_bf16(a, bf[nf],
                                                                acc[mf][nf], 0, 0, 0);
      }
    }
    __builtin_amdgcn_s_setprio(0);

    if (t + 1 < NT) {
      VMC("0");
      barrier_();
    }
    cur ^= 1;
  }

  // ---------------- epilogue ----------------
  int col16 = lane & 15, rgrp = lane >> 4;
#pragma unroll
  for (int mf = 0; mf < 8; ++mf) {
    int grow0 = bm * 256 + wm * 128 + mf * 16 + rgrp * 4;
#pragma unroll
    for (int nf = 0; nf < 4; ++nf) {
      int gc = bn * 256 + wn * 64 + nf * 16 + col16;
      if (gc < 512) {  // z columns (block-uniform: bn<2)
        float b = bz[gc];
#pragma unroll
        for (int j = 0; j < 4; ++j) {
          float z = sigmoidf_(acc[mf][nf][j] + b);
          Zb[(size_t)(grow0 + j) * 512 + gc] = (__bf16)z;
        }
      } else {         // r columns
        int c = gc - 512;
        float b = br[c];
#pragma unroll
        for (int j = 0; j < 4; ++j) {
          int grow = grow0 + j;
          float r = sigmoidf_(acc[mf][nf][j] + b);
          float hd = (float)A1[(size_t)grow * 1024 + 512 + c];
          RHout[(size_t)grow * 512 + c] = (__bf16)(r * hd);
        }
      }
    }
  }
}

// ---------------- gemm8: gemm1 (BK=64, NT=16, 2 blocks/CU) ----------------
// LDS layout (16B units): (row m, chunk ku in 0..7) at unit m*8 + (ku ^ (m&7)).
__global__ __launch_bounds__(512, 4) void gemm8_k(
    const __bf16* __restrict__ A1, const __bf16* __restrict__ RH,
    const __bf16* __restrict__ Bt,
    const __bf16* __restrict__ Zb, const float* __restrict__ bh,
    float* __restrict__ out) {
  constexpr int SBUF = 2048;                  // A 1024 | B 1024 units
  __shared__ bf16x8 ldsv[2 * SBUF];           // 64KB -> 2 blocks/CU
  constexpr int NT = 16;                      // K=1024, BK=64

  int bid = blockIdx.x;
  int swz = (bid & 7) * 64 + (bid >> 3);      // bijective XCD swizzle (512=8x64)
  int bm = swz >> 2, bn = swz & 3;            // 128 x 4
  int tid = threadIdx.x, lane = tid & 63, wid = tid >> 6;
  int wm = wid >> 2, wn = wid & 3;            // 2M x 4N waves: 64 x 32

  int U0 = wid * 128 + lane, U1 = U0 + 64;
  auto srcoff = [&](int U, int ldb) {
    int r = U >> 3;
    return r * ldb + (((U & 7) ^ (r & 7)) << 4);   // bytes
  };
  int oA0x = srcoff(U0, 2048), oA1x = srcoff(U1, 2048);  // A1 (xd, t<8)
  int oA0r = srcoff(U0, 1024), oA1r = srcoff(U1, 1024);  // RH  (t>=8)
  int oB0 = srcoff(U0, 2048), oB1 = srcoff(U1, 2048);

  auto stage = [&](int t, int buf) {
    const char* gA;
    int a0, a1;
    if (t < 8) {
      gA = (const char*)A1 + (size_t)bm * 128 * 2048 + t * 128;
      a0 = oA0x; a1 = oA1x;
    } else {
      gA = (const char*)RH + (size_t)bm * 128 * 1024 + (t - 8) * 128;
      a0 = oA0r; a1 = oA1r;
    }
    __builtin_amdgcn_global_load_lds((g_vp*)(gA + a0),
        (lds_vp*)(ldsv + buf * SBUF + wid * 128), 16, 0, 0);
    __builtin_amdgcn_global_load_lds((g_vp*)(gA + a1),
        (lds_vp*)(ldsv + buf * SBUF + wid * 128 + 64), 16, 0, 0);
    const char* gB = (const char*)Bt + (size_t)bn * 128 * 2048 + t * 128;
    __builtin_amdgcn_global_load_lds((g_vp*)(gB + oB0),
        (lds_vp*)(ldsv + buf * SBUF + 1024 + wid * 128), 16, 0, 0);
    __builtin_amdgcn_global_load_lds((g_vp*)(gB + oB1),
        (lds_vp*)(ldsv + buf * SBUF + 1024 + wid * 128 + 64), 16, 0, 0);
  };

  int hi = lane >> 4;
  int ra = wm * 64 + (lane & 15);             // + mf*16
  int rb = wn * 32 + (lane & 15);             // + nf*16
  int sa = ra & 7, sb = rb & 7;

  f32x4 acc[4][2] = {};

  stage(0, 0);
  VMC("0");
  barrier_();

  int cur = 0;
  for (int t = 0; t < NT; ++t) {
    if (t + 1 < NT) stage(t + 1, cur ^ 1);
    int base = cur * SBUF;

    __builtin_amdgcn_s_setprio(1);
#pragma unroll
    for (int kk = 0; kk < 2; ++kk) {
      int ku = kk * 4 + hi;
      bf16x8 bf[2];
#pragma unroll
      for (int nf = 0; nf < 2; ++nf)
        bf[nf] = ldsv[base + 1024 + (rb + nf * 16) * 8 + (ku ^ sb)];
#pragma unroll
      for (int mf = 0; mf < 4; ++mf) {
        bf16x8 a = ldsv[base + (ra + mf * 16) * 8 + (ku ^ sa)];
#pragma unroll
        for (int nf = 0; nf < 2; ++nf)
          acc[mf][nf] = __builtin_amdgcn_mfma_f32_16x16x32_bf16(a, bf[nf],
                                                                acc[mf][nf], 0, 0, 0);
      }
    }
    __builtin_amdgcn_s_setprio(0);

    if (t + 1 < NT) {
      VMC("0");
      barrier_();
    }
    cur ^= 1;
  }

  int col16 = lane & 15, rgrp = lane >> 4;
#pragma unroll
  for (int mf = 0; mf < 4; ++mf) {
    int grow0 = bm * 128 + wm * 64 + mf * 16 + rgrp * 4;
#pragma unroll
    for (int nf = 0; nf < 2; ++nf) {
      int gc = bn * 128 + wn * 32 + nf * 16 + col16;
      float b = bh[gc];
#pragma unroll
      for (int j = 0; j < 4; ++j) {
        int grow = grow0 + j;
        float hh = tanhf(acc[mf][nf][j] + b);
        float hd = (float)A1[(size_t)grow * 1024 + 512 + gc];
        float z = (float)Zb[(size_t)grow * 512 + gc];
        out[(size_t)grow * 512 + gc] = (1.f - z) * hd + z * hh;
      }
    }
  }
}

// ---------------- launch ----------------
extern "C" void kernel_launch(void* const* d_in, const int* in_sizes, int n_in,
                              void* d_out, int out_size, void* d_ws, size_t ws_size,
                              hipStream_t stream) {
  const float* inputs = (const float*)d_in[0];
  const float* h_prev = (const float*)d_in[1];
  const float* W_z = (const float*)d_in[2];
  const float* U_z = (const float*)d_in[3];
  const float* b_z = (const float*)d_in[4];
  const float* W_r = (const float*)d_in[5];
  const float* U_r = (const float*)d_in[6];
  const float* b_r = (const float*)d_in[7];
  const float* W_h = (const float*)d_in[8];
  const float* U_h = (const float*)d_in[9];
  const float* b_h = (const float*)d_in[10];
  const float* gxd = (const float*)d_in[11];
  const float* ghd = (const float*)d_in[12];
  const float* mimp = (const float*)d_in[13];
  float* out = (float*)d_out;

  char* ws = (char*)d_ws;
  __bf16* A1  = (__bf16*)(ws);                  // 16384x1024 bf16 = 32MB
  __bf16* RH  = (__bf16*)(ws + 33554432);       // 16384x512 bf16 = 16MB
  __bf16* Zb  = (__bf16*)(ws + 50331648);       // 16384x512 bf16 = 16MB
  __bf16* Wzr = (__bf16*)(ws + 67108864);       // 1024x1024 bf16 = 2MB
  __bf16* Wht = (__bf16*)(ws + 69206016);       // 512x1024 bf16  = 1MB

  prep_pack_k<<<4480, 256, 0, stream>>>(inputs, h_prev, gxd, ghd, mimp, A1,
                                        W_z, U_z, W_r, U_r, W_h, U_h, Wzr, Wht);
  gemm9_k<<<256, 512, 0, stream>>>(A1, Wzr, Zb, RH, b_z, b_r);
  gemm8_k<<<512, 512, 0, stream>>>(A1, RH, Wht, Zb, b_h, out);
}